// Round 2
// baseline (51.295 us; speedup 1.0000x reference)
//
#include <hip/hip_runtime.h>

// out[b,o] = min_i max(x[b,i], w[i,o])   (forward of the STE expression == hard min)
// B=512, I=512, O=1024, fp32.
//
// K-split over I (4 segments) for occupancy: 512 blocks = 2/CU = 8 waves/CU.
// Partial mins combined with atomicMin on uint (all values positive => uint
// order == float order; exact min => bit-deterministic). d_out pre-filled with
// 0x7F7F7F7F which exceeds any valid result's bit pattern.

#define B_DIM 512
#define I_DIM 512
#define O_DIM 1024

#define BM 64
#define BN 64
#define KI 32
#define SEG 128
#define NSPLIT (I_DIM / SEG)   // 4
#define NCHUNK (SEG / KI)      // 4
#define XPAD 68                // row stride 272B: 16B-aligned rows, +4 breaks pow2

__global__ __launch_bounds__(256, 2) void SmoothSTEMinMax_kernel(
    const float* __restrict__ x,       // [B, I]
    const float* __restrict__ w,       // [I, O]
    unsigned int* __restrict__ out) {  // [B, O] as uint bits
  __shared__ float xs[KI][XPAD];       // transposed x tile: xs[ki][row]
  __shared__ float ws[KI][BN];         // ws[ki][col]

  const int tid = threadIdx.x;
  const int b0 = blockIdx.x * BM;
  const int o0 = blockIdx.y * BN;
  const int ibase = blockIdx.z * SEG;

  // staging maps (global-coalesced)
  const int xk = tid & 31;         // ki for x (contiguous along I)
  const int xr = tid >> 5;         // row base (0..7), 8 passes of +8
  const int wk = tid >> 4;         // ki base (0..15), 2 passes of +16
  const int wc = (tid & 15) * 4;   // col (float4, contiguous along O)

  // compute map: 4 rows x 4 cols per thread
  const int ty = tid >> 4;         // 0..15 -> rows ty*4..ty*4+3
  const int tx = tid & 15;         // 0..15 -> cols tx*4..tx*4+3

  float xreg[8];
  float4 wreg[2];

  // prologue: prefetch chunk 0
#pragma unroll
  for (int p = 0; p < 8; ++p)
    xreg[p] = x[(b0 + xr + 8 * p) * I_DIM + ibase + xk];
#pragma unroll
  for (int p = 0; p < 2; ++p)
    wreg[p] = *reinterpret_cast<const float4*>(&w[(ibase + wk + 16 * p) * O_DIM + o0 + wc]);

  float acc[4][4];
#pragma unroll
  for (int r = 0; r < 4; ++r)
#pragma unroll
    for (int c = 0; c < 4; ++c) acc[r][c] = 3.402823466e+38f;

  for (int ch = 0; ch < NCHUNK; ++ch) {
    // staged regs -> LDS
#pragma unroll
    for (int p = 0; p < 8; ++p) xs[xk][xr + 8 * p] = xreg[p];
#pragma unroll
    for (int p = 0; p < 2; ++p)
      *reinterpret_cast<float4*>(&ws[wk + 16 * p][wc]) = wreg[p];
    __syncthreads();

    // issue next chunk's global loads; they land during compute
    if (ch + 1 < NCHUNK) {
      const int i0 = ibase + (ch + 1) * KI;
#pragma unroll
      for (int p = 0; p < 8; ++p)
        xreg[p] = x[(b0 + xr + 8 * p) * I_DIM + i0 + xk];
#pragma unroll
      for (int p = 0; p < 2; ++p)
        wreg[p] = *reinterpret_cast<const float4*>(&w[(i0 + wk + 16 * p) * O_DIM + o0 + wc]);
    }

    // min-max inner loop: 32 VALU ops per ki per thread, 2 broadcast b128 reads
#pragma unroll
    for (int ki = 0; ki < KI; ++ki) {
      const float4 xv = *reinterpret_cast<const float4*>(&xs[ki][ty * 4]);
      const float4 wv = *reinterpret_cast<const float4*>(&ws[ki][tx * 4]);
      const float xa[4] = {xv.x, xv.y, xv.z, xv.w};
      const float wa[4] = {wv.x, wv.y, wv.z, wv.w};
#pragma unroll
      for (int r = 0; r < 4; ++r)
#pragma unroll
        for (int c = 0; c < 4; ++c)
          acc[r][c] = fminf(acc[r][c], fmaxf(xa[r], wa[c]));
    }
    __syncthreads();
  }

  // combine partial mins across the 4 K-segments
#pragma unroll
  for (int r = 0; r < 4; ++r)
#pragma unroll
    for (int c = 0; c < 4; ++c)
      atomicMin(&out[(b0 + ty * 4 + r) * O_DIM + o0 + tx * 4 + c],
                __float_as_uint(acc[r][c]));
}

extern "C" void kernel_launch(void* const* d_in, const int* in_sizes, int n_in,
                              void* d_out, int out_size, void* d_ws, size_t ws_size,
                              hipStream_t stream) {
  const float* x = (const float*)d_in[0];   // [512, 512]
  const float* w = (const float*)d_in[1];   // [512, 1024]
  unsigned int* out = (unsigned int*)d_out; // [512, 1024]

  // 0x7F7F7F7F as uint > bit pattern of any value in [0, 1] -> valid +inf-like init
  hipMemsetAsync(d_out, 0x7F, (size_t)out_size * sizeof(float), stream);

  dim3 grid(B_DIM / BM, O_DIM / BN, NSPLIT);  // 8 x 16 x 4 = 512 blocks
  SmoothSTEMinMax_kernel<<<grid, 256, 0, stream>>>(x, w, out);
}

// Round 3
// 19.787 us; speedup vs baseline: 2.5923x; 2.5923x over previous
//
#include <hip/hip_runtime.h>

// out[b,o] = min_i max(x[b,i], w[i,o])   (forward of STE expr == hard min; exact)
// B=512, I=512, O=1024, fp32, all values in [0,1).
//
// Sort-scan algorithm: per row b, sort x[b,:] ascending (keeping indices).
// Scan i in ascending-x order keeping running min A. Since every later
// candidate max(x_(j),w) >= x_(j) >= x_(next), once no lane has A > x_(next)
// the wave can stop — EXACT early exit. Expected ~64/512 iterations per wave
// for uniform data.

#define B_DIM 512
#define I_DIM 512
#define O_DIM 1024
#define U 8

// ---------- kernel 1: per-row bitonic sort of (valbits<<32 | idx) ----------
__global__ __launch_bounds__(256) void sort_rows_kernel(
    const float* __restrict__ x, unsigned long long* __restrict__ keys) {
  __shared__ unsigned long long s[I_DIM];
  const int b = blockIdx.x;
  const int t = threadIdx.x;
#pragma unroll
  for (int p = 0; p < 2; ++p) {
    const int i = t + 256 * p;
    s[i] = ((unsigned long long)__float_as_uint(x[b * I_DIM + i]) << 32) | (unsigned)i;
  }
  for (int size = 2; size <= I_DIM; size <<= 1) {
    for (int stride = size >> 1; stride > 0; stride >>= 1) {
      __syncthreads();
      const int lo = t & (stride - 1);
      const int i = ((t - lo) << 1) | lo;
      const int j = i | stride;
      const unsigned long long a = s[i], c = s[j];
      const bool asc = (i & size) == 0;
      if ((a > c) == asc) { s[i] = c; s[j] = a; }
    }
  }
  __syncthreads();
#pragma unroll
  for (int p = 0; p < 2; ++p) {
    const int i = t + 256 * p;
    keys[b * I_DIM + i] = s[i];
  }
}

// ---------- kernel 2: early-exit scan ----------
__global__ __launch_bounds__(256, 8) void scan_kernel(
    const unsigned long long* __restrict__ keys,
    const float* __restrict__ w, float* __restrict__ out) {
  __shared__ unsigned long long kl[I_DIM];
  const int b = blockIdx.x;
  const int t = threadIdx.x;
  const int o = blockIdx.y * 256 + t;
  kl[t] = keys[b * I_DIM + t];
  kl[t + 256] = keys[b * I_DIM + t + 256];
  __syncthreads();

  float A = 3.402823466e+38f;
  int k = 0;
  while (true) {
    // unpack U sorted entries; wave-uniform -> hoist to SGPRs
    float xv[U];
    const float* wrow[U];
#pragma unroll
    for (int u = 0; u < U; ++u) {
      const unsigned long long kk = kl[k + u];
      const unsigned xb = (unsigned)__builtin_amdgcn_readfirstlane((int)(kk >> 32));
      const int row = __builtin_amdgcn_readfirstlane((int)(kk & 0xffffffffull));
      xv[u] = __uint_as_float(xb);
      wrow[u] = w + row * O_DIM;
    }
    // issue all U loads (coalesced dword per wave; scalar base + vector offset)
    float wv[U];
#pragma unroll
    for (int u = 0; u < U; ++u) wv[u] = wrow[u][o];
#pragma unroll
    for (int u = 0; u < U; ++u) A = fminf(A, fmaxf(xv[u], wv[u]));
    k += U;
    if (k >= I_DIM) break;
    const float xnext = __uint_as_float((unsigned)(kl[k] >> 32));
    if (!__any(A > xnext)) break;  // exact: later max(x_j,w) >= x_j >= xnext >= A
  }
  out[b * O_DIM + o] = A;
}

// ---------- fallback (if d_ws too small): R1 brute-force tiled kernel ----------
#define BM 32
#define BN 64
#define KI 32
#define NCHUNK (I_DIM / KI)

__global__ __launch_bounds__(256, 1) void brute_kernel(
    const float* __restrict__ x, const float* __restrict__ w,
    float* __restrict__ out) {
  __shared__ float xs[KI][BM + 1];
  __shared__ float ws[KI][BN];
  const int tid = threadIdx.x;
  const int tx = tid & 15, ty = tid >> 4;
  const int b0 = blockIdx.x * BM, o0 = blockIdx.y * BN;
  const int xr = tid >> 5, xk = tid & 31;
  const int wk = tid >> 4, wc = (tid & 15) * 4;
  float xreg[4];
  float4 wreg[2];
#pragma unroll
  for (int p = 0; p < 4; ++p) xreg[p] = x[(b0 + xr + 8 * p) * I_DIM + xk];
#pragma unroll
  for (int p = 0; p < 2; ++p)
    wreg[p] = *reinterpret_cast<const float4*>(&w[(wk + 16 * p) * O_DIM + o0 + wc]);
  float acc[2][4];
#pragma unroll
  for (int r = 0; r < 2; ++r)
#pragma unroll
    for (int c = 0; c < 4; ++c) acc[r][c] = 3.402823466e+38f;
  for (int ch = 0; ch < NCHUNK; ++ch) {
#pragma unroll
    for (int p = 0; p < 4; ++p) xs[xk][xr + 8 * p] = xreg[p];
#pragma unroll
    for (int p = 0; p < 2; ++p)
      *reinterpret_cast<float4*>(&ws[wk + 16 * p][wc]) = wreg[p];
    __syncthreads();
    if (ch + 1 < NCHUNK) {
      const int i0 = (ch + 1) * KI;
#pragma unroll
      for (int p = 0; p < 4; ++p) xreg[p] = x[(b0 + xr + 8 * p) * I_DIM + i0 + xk];
#pragma unroll
      for (int p = 0; p < 2; ++p)
        wreg[p] = *reinterpret_cast<const float4*>(&w[(i0 + wk + 16 * p) * O_DIM + o0 + wc]);
    }
#pragma unroll
    for (int ki = 0; ki < KI; ++ki) {
      const float xv0 = xs[ki][ty * 2 + 0];
      const float xv1 = xs[ki][ty * 2 + 1];
      const float4 wv = *reinterpret_cast<const float4*>(&ws[ki][tx * 4]);
      acc[0][0] = fminf(acc[0][0], fmaxf(xv0, wv.x));
      acc[0][1] = fminf(acc[0][1], fmaxf(xv0, wv.y));
      acc[0][2] = fminf(acc[0][2], fmaxf(xv0, wv.z));
      acc[0][3] = fminf(acc[0][3], fmaxf(xv0, wv.w));
      acc[1][0] = fminf(acc[1][0], fmaxf(xv1, wv.x));
      acc[1][1] = fminf(acc[1][1], fmaxf(xv1, wv.y));
      acc[1][2] = fminf(acc[1][2], fmaxf(xv1, wv.z));
      acc[1][3] = fminf(acc[1][3], fmaxf(xv1, wv.w));
    }
    __syncthreads();
  }
#pragma unroll
  for (int r = 0; r < 2; ++r) {
    const float4 v = make_float4(acc[r][0], acc[r][1], acc[r][2], acc[r][3]);
    *reinterpret_cast<float4*>(&out[(b0 + ty * 2 + r) * O_DIM + o0 + tx * 4]) = v;
  }
}

extern "C" void kernel_launch(void* const* d_in, const int* in_sizes, int n_in,
                              void* d_out, int out_size, void* d_ws, size_t ws_size,
                              hipStream_t stream) {
  const float* x = (const float*)d_in[0];   // [512, 512]
  const float* w = (const float*)d_in[1];   // [512, 1024]
  float* out = (float*)d_out;               // [512, 1024]

  const size_t keys_bytes = (size_t)B_DIM * I_DIM * sizeof(unsigned long long);
  if (ws_size >= keys_bytes) {
    unsigned long long* keys = (unsigned long long*)d_ws;
    sort_rows_kernel<<<B_DIM, 256, 0, stream>>>(x, keys);
    dim3 grid(B_DIM, O_DIM / 256);  // 512 x 4
    scan_kernel<<<grid, 256, 0, stream>>>(keys, w, out);
  } else {
    dim3 grid(B_DIM / BM, O_DIM / BN);
    brute_kernel<<<grid, 256, 0, stream>>>(x, w, out);
  }
}

// Round 4
// 14.344 us; speedup vs baseline: 3.5761x; 1.3795x over previous
//
#include <hip/hip_runtime.h>

// out[b,o] = min_i max(x[b,i], w[i,o])   (forward of STE expr == hard min)
// B=512, I=512, O=1024, fp32, values uniform in [0,1).
//
// Fused bucket-sort + early-exit scan, one block per (row, o-half):
//  Phase A: counting-sort x[b,:] into 256 value buckets in LDS (hist ->
//           shfl prefix scan -> scatter). Unordered within bucket.
//  Phase B: scan entries in bucket-ascending order, running min A.
//           Exit when no lane has A > bucket_lo(next entry): every
//           unvisited entry has value >= its bucket lower bound, so
//           max(x_i, w) >= x_i >= thresh >= A  => exact to ~6e-8
//           (fp rounding slop of the bucket boundary), << 3.4e-3 threshold.

#define B_DIM 512
#define I_DIM 512
#define O_DIM 1024
#define NBUCK 256
#define U 8

__global__ __launch_bounds__(256, 4) void SmoothSTEMinMax_fused(
    const float* __restrict__ x,     // [B, I]
    const float* __restrict__ w,     // [I, O]
    float* __restrict__ out) {       // [B, O]
  __shared__ unsigned int hist[NBUCK];
  __shared__ unsigned int wssum[4];
  __shared__ unsigned long long s[I_DIM];   // (x bits << 32) | idx, bucket-ordered

  const int t = threadIdx.x;
  const int b = blockIdx.x;
  const int o0 = blockIdx.y * 512;

  // ---- Phase A: counting sort by value bucket ----
  float xv[2];
  int bp[2];
#pragma unroll
  for (int p = 0; p < 2; ++p) {
    xv[p] = x[b * I_DIM + t + 256 * p];
    int bb = (int)(xv[p] * 256.0f);
    bp[p] = bb > 255 ? 255 : (bb < 0 ? 0 : bb);
  }
  hist[t] = 0;
  __syncthreads();
#pragma unroll
  for (int p = 0; p < 2; ++p) atomicAdd(&hist[bp[p]], 1u);
  __syncthreads();

  // exclusive prefix sum over 256 counters: per-wave shfl scan + wave offsets
  const unsigned cnt = hist[t];
  unsigned v = cnt;
  const int lane = t & 63;
#pragma unroll
  for (int d = 1; d < 64; d <<= 1) {
    const unsigned n = __shfl_up(v, d, 64);
    if (lane >= d) v += n;
  }
  if (lane == 63) wssum[t >> 6] = v;
  __syncthreads();
  unsigned add = 0;
#pragma unroll
  for (int ww = 0; ww < 4; ++ww)
    if (ww < (t >> 6)) add += wssum[ww];
  const unsigned excl = v + add - cnt;
  __syncthreads();
  hist[t] = excl;   // bucket cursor
  __syncthreads();

  // scatter (unordered within bucket — OK, threshold uses bucket lower bound)
#pragma unroll
  for (int p = 0; p < 2; ++p) {
    const unsigned pos = atomicAdd(&hist[bp[p]], 1u);
    s[pos] = ((unsigned long long)__float_as_uint(xv[p]) << 32) | (unsigned)(t + 256 * p);
  }
  __syncthreads();

  // ---- Phase B: early-exit scan (per-wave independent from here) ----
  float A0 = 3.402823466e+38f, A1 = A0;
  const int oa = o0 + t;
  const int ob = o0 + 256 + t;
  int k = 0;
  while (true) {
    float xs_[U];
    const float* wp[U];
#pragma unroll
    for (int u = 0; u < U; ++u) {
      const unsigned long long kk = s[k + u];                       // LDS broadcast
      const int row = __builtin_amdgcn_readfirstlane((int)(unsigned)(kk & 0xffffffffull));
      const unsigned xb = (unsigned)__builtin_amdgcn_readfirstlane((int)(kk >> 32));
      xs_[u] = __uint_as_float(xb);
      wp[u] = w + row * O_DIM;                                      // SGPR base
    }
    float w0[U], w1[U];
#pragma unroll
    for (int u = 0; u < U; ++u) { w0[u] = wp[u][oa]; w1[u] = wp[u][ob]; }
#pragma unroll
    for (int u = 0; u < U; ++u) {
      A0 = fminf(A0, fmaxf(xs_[u], w0[u]));
      A1 = fminf(A1, fmaxf(xs_[u], w1[u]));
    }
    k += U;
    if (k >= I_DIM) break;
    const float xnext = __uint_as_float((unsigned)(s[k] >> 32));
    const int bn = (int)(xnext * 256.0f);
    const float thresh = (float)bn * 0.00390625f;   // bucket lower bound
    if (!__any(A0 > thresh || A1 > thresh)) break;  // exact early exit
  }
  out[b * O_DIM + oa] = A0;
  out[b * O_DIM + ob] = A1;
}

extern "C" void kernel_launch(void* const* d_in, const int* in_sizes, int n_in,
                              void* d_out, int out_size, void* d_ws, size_t ws_size,
                              hipStream_t stream) {
  const float* x = (const float*)d_in[0];   // [512, 512]
  const float* w = (const float*)d_in[1];   // [512, 1024]
  float* out = (float*)d_out;               // [512, 1024]

  dim3 grid(B_DIM, O_DIM / 512);            // 512 x 2 = 1024 blocks
  SmoothSTEMinMax_fused<<<grid, 256, 0, stream>>>(x, w, out);
}